// Round 5
// baseline (523.576 us; speedup 1.0000x reference)
//
#include <hip/hip_runtime.h>
#include <cstdint>

// FracAttention: B=2, S=2048, D_MODEL=2048, H=16, DK=128
#define S_LEN   2048
#define DMODEL  2048
#define NHEADS  16
#define DK      128
#define MROWS   4096   // B*S

typedef _Float16 f16;
using f16x8 = __attribute__((ext_vector_type(8))) _Float16;
using f16x4 = __attribute__((ext_vector_type(4))) _Float16;
using f32x4 = __attribute__((ext_vector_type(4))) float;
using f32x16 = __attribute__((ext_vector_type(16))) float;

typedef const __attribute__((address_space(1))) unsigned int gu32;
typedef __attribute__((address_space(3))) unsigned int lu32;

__device__ __forceinline__ void gl2lds16(const void* g, void* l) {
    // async global->LDS, 16 B per lane; LDS dest = wave-uniform base + lane*16
    __builtin_amdgcn_global_load_lds((gu32*)g, (lu32*)l, 16, 0, 0);
}

// ---------------------------------------------------------------------------
// fp32 -> fp16 convert, all 7 tensors in one dispatch.
// ---------------------------------------------------------------------------
__global__ __launch_bounds__(256) void cvt_all(
    const float* __restrict__ q, const float* __restrict__ k,
    const float* __restrict__ v, const float* __restrict__ wq,
    const float* __restrict__ wk, const float* __restrict__ wv,
    const float* __restrict__ wo,
    f16* cq, f16* ck, f16* cv, f16* cwq, f16* cwk, f16* cwv, f16* cwo)
{
    const int b = blockIdx.x;
    const float* src; f16* dst; int base;
    if      (b <  8192) { src = q;  dst = cq;  base = b; }
    else if (b < 16384) { src = k;  dst = ck;  base = b - 8192; }
    else if (b < 24576) { src = v;  dst = cv;  base = b - 16384; }
    else if (b < 28672) { src = wq; dst = cwq; base = b - 24576; }
    else if (b < 32768) { src = wk; dst = cwk; base = b - 28672; }
    else if (b < 36864) { src = wv; dst = cwv; base = b - 32768; }
    else                { src = wo; dst = cwo; base = b - 36864; }
    const int i = base * 256 + threadIdx.x;
    float4 x = ((const float4*)src)[i];
    f16x4 o; o[0] = (f16)x.x; o[1] = (f16)x.y; o[2] = (f16)x.z; o[3] = (f16)x.w;
    ((f16x4*)dst)[i] = o;
}

// ---------------------------------------------------------------------------
// fp16 MFMA GEMM core, 32x32x16 MFMA.
// C[M][N] = A[M][K] @ W[N][K]^T + bias;  M=MROWS, N=K=DMODEL fixed.
// 128x128 tile, BK=32, 2x2 waves of 64x64, each 2x2 of 32x32x16.
// mode 0: fp32 out [M][N]
// mode 1: f16 out head-permuted  [B,H,S,DK]         (K)
// mode 2: f16 out head-permuted + transposed [B,H,DK,S] (V -> VT)
// mode 3: f16 out head-permuted, scaled by sa[h]/max(sb[h],1)  (Q)
// NOTE: aliasing hazard — callers must NOT alias Cout with any buffer read
// by the SAME dispatch (R4 bug: fused qkv + XCD swizzle interleaved z, so
// K-proj wrote Kh=c_q while Q-proj blocks still read c_q).
// ---------------------------------------------------------------------------
__device__ __forceinline__ void gemm_core(
    const f16* __restrict__ A, const f16* __restrict__ W,
    const float* __restrict__ bias, void* __restrict__ Cout,
    int bmb, int bnb, int mode,
    const float* __restrict__ sa, const float* __restrict__ sb)
{
    __shared__ f16 As[128 * 32];   // [m][k-chunk of 32]
    __shared__ f16 Bs[128 * 32];   // [n][k-chunk of 32]

    const int tid = threadIdx.x;
    const int bm = bmb * 128;
    const int bn = bnb * 128;
    const int wid = tid >> 6;
    const int ln31 = tid & 31;          // lane&31 -> C/D col (n), A/B row
    const int ln5 = (tid & 63) >> 5;    // lane>>5 -> k-half selector
    const int wm = (wid >> 1) * 64;
    const int wn = (wid & 1) * 64;
    const int K = DMODEL, N = DMODEL;

    f32x16 acc[2][2];
#pragma unroll
    for (int i = 0; i < 2; ++i)
#pragma unroll
        for (int j = 0; j < 2; ++j)
#pragma unroll
            for (int r = 0; r < 16; ++r) acc[i][j][r] = 0.0f;

    const int sr = tid >> 2;
    const int ke = (tid & 3) * 8;
    const f16* ga0 = A + (size_t)(bm + sr) * K + ke;
    const f16* ga1 = A + (size_t)(bm + 64 + sr) * K + ke;
    const f16* gb0 = W + (size_t)(bn + sr) * K + ke;
    const f16* gb1 = W + (size_t)(bn + 64 + sr) * K + ke;
    f16* la0 = As + tid * 8;
    f16* la1 = As + 2048 + tid * 8;
    f16* lb0 = Bs + tid * 8;
    f16* lb1 = Bs + 2048 + tid * 8;

    for (int k0 = 0; k0 < K; k0 += 32) {
        __syncthreads();
        gl2lds16(ga0 + k0, la0);
        gl2lds16(ga1 + k0, la1);
        gl2lds16(gb0 + k0, lb0);
        gl2lds16(gb1 + k0, lb1);
        __syncthreads();

#pragma unroll
        for (int s = 0; s < 2; ++s) {
            f16x8 af[2], bf[2];
#pragma unroll
            for (int i = 0; i < 2; ++i)
                af[i] = *(const f16x8*)&As[(wm + i * 32 + ln31) * 32 + s * 16 + ln5 * 8];
#pragma unroll
            for (int j = 0; j < 2; ++j)
                bf[j] = *(const f16x8*)&Bs[(wn + j * 32 + ln31) * 32 + s * 16 + ln5 * 8];
#pragma unroll
            for (int i = 0; i < 2; ++i)
#pragma unroll
                for (int j = 0; j < 2; ++j)
                    acc[i][j] = __builtin_amdgcn_mfma_f32_32x32x16_f16(
                        af[i], bf[j], acc[i][j], 0, 0, 0);
        }
    }

    // epilogue: 32x32 C/D layout col=lane&31, row=(reg&3)+8*(reg>>2)+4*(lane>>5)
#pragma unroll
    for (int j = 0; j < 2; ++j) {
        const int n = bn + wn + j * 32 + ln31;
        const float bn_ = bias[n];
        const int h = n >> 7;           // n / DK
        const int d = n & (DK - 1);
        float scq = 1.0f;
        if (mode == 3) scq = sa[h] / fmaxf(sb[h], 1.0f);
#pragma unroll
        for (int i = 0; i < 2; ++i) {
#pragma unroll
            for (int rg = 0; rg < 4; ++rg) {
                const int m0 = bm + wm + i * 32 + rg * 8 + ln5 * 4;  // 4 consecutive m
                if (mode == 2) {
                    // VT: idx = ((bb*H+h)*DK+d)*S + ss ; 4 consecutive ss -> 8B store
                    const int bb = m0 >> 11;
                    const int ss = m0 & (S_LEN - 1);
                    f16x4 pk;
#pragma unroll
                    for (int r = 0; r < 4; ++r)
                        pk[r] = (f16)(acc[i][j][rg * 4 + r] + bn_);
                    *(f16x4*)&((f16*)Cout)[(((size_t)(bb * NHEADS + h) * DK + d)
                                            * S_LEN + ss)] = pk;
                } else {
#pragma unroll
                    for (int r = 0; r < 4; ++r) {
                        const int m = m0 + r;
                        float v = acc[i][j][rg * 4 + r] + bn_;
                        if (mode == 0) {
                            ((float*)Cout)[(size_t)m * N + n] = v;
                        } else {
                            const int bb = m >> 11;
                            const int ss = m & (S_LEN - 1);
                            if (mode == 3) v *= scq;
                            ((f16*)Cout)[(((size_t)(bb * NHEADS + h) * S_LEN + ss)
                                          * DK + d)] = (f16)v;
                        }
                    }
                }
            }
        }
    }
}

// One projection GEMM, 512 blocks, XCD-swizzled:
// id&7 = XCD; each XCD owns 2 bn strips (1 MB of weights) -> L2-resident.
__global__ __launch_bounds__(256) void proj_gemm(
    const f16* A, const f16* W, const float* bias, void* O,
    int mode, const float* sa, const float* sb)
{
    const int id = blockIdx.x;
    const int x = id & 7;
    const int t = id >> 3;              // 0..63
    const int bn = x * 2 + (t >> 5);    // 0..15
    const int bm = t & 31;
    gemm_core(A, W, bias, O, bm, bn, mode, sa, sb);
}

// ---------------------------------------------------------------------------
// Flash attention v4 (fp16 MFMA, reduction-free softmax) — unchanged from R3.
// ---------------------------------------------------------------------------
__global__ __launch_bounds__(256, 2) void flash_v4(
    const f16* __restrict__ Qg, const f16* __restrict__ Kg,
    const f16* __restrict__ VTg, f16* __restrict__ AO)
{
    __shared__ f16 Ks[4 * 64 * 32];    // [kc][c][32]
    __shared__ f16 Vs[2 * 128 * 32];   // [cc][d][32]
    __shared__ f16 Ps[2 * 128 * 32];   // [cc][q][32]
    __shared__ float l_buf[2 * 128];   // [wc][q]

    const int tid = threadIdx.x;
    const int wid = tid >> 6;
    const int ln = tid & 15;
    const int quad = (tid & 63) >> 4;
    const int wq = wid & 1;
    const int wc = wid >> 1;
    const int bh = blockIdx.y;
    const int q0 = blockIdx.x * 128;

    // Q fragments to registers (wave's 64 q-rows, pre-scaled)
    f16x8 qf[4][4];
    const f16* Qbase = Qg + ((size_t)bh * S_LEN + q0 + wq * 64) * DK;
#pragma unroll
    for (int nt = 0; nt < 4; ++nt)
#pragma unroll
        for (int kc = 0; kc < 4; ++kc)
            qf[nt][kc] = *(const f16x8*)(Qbase + (size_t)(nt * 16 + ln) * DK
                                         + kc * 32 + quad * 8);

    f32x4 o[4][4];     // [mtq over q][ntd over d]
    float lp[4] = {0.f, 0.f, 0.f, 0.f};
#pragma unroll
    for (int i = 0; i < 4; ++i)
#pragma unroll
        for (int j = 0; j < 4; ++j)
            o[i][j] = (f32x4){0.f, 0.f, 0.f, 0.f};

    const f16* Kgb = Kg + (size_t)bh * S_LEN * DK;
    const f16* Vgb = VTg + (size_t)bh * DK * S_LEN;
    const int srow = tid >> 2;
    const int soff = (tid & 3) * 8;

    for (int kt = 0; kt < S_LEN / 64; ++kt) {
        __syncthreads();   // prior QK/PV done reading Ks/Vs/Ps
#pragma unroll
        for (int j = 0; j < 4; ++j)
            gl2lds16(Kgb + (size_t)(kt * 64 + srow) * DK + j * 32 + soff,
                     Ks + j * 2048 + tid * 8);
#pragma unroll
        for (int j = 0; j < 4; ++j)
            gl2lds16(Vgb + (size_t)(srow + (j & 1) * 64) * S_LEN
                         + kt * 64 + (j >> 1) * 32 + soff,
                     Vs + (j >> 1) * 4096 + (j & 1) * 2048 + tid * 8);
        __syncthreads();   // staging complete

        // S^T = K Q^T : wave quadrant [32 c][64 q], 32 MFMAs, 8 LDS reads
        f32x4 s[2][4];
#pragma unroll
        for (int mt = 0; mt < 2; ++mt)
#pragma unroll
            for (int nt = 0; nt < 4; ++nt)
                s[mt][nt] = (f32x4){0.f, 0.f, 0.f, 0.f};
#pragma unroll
        for (int kc = 0; kc < 4; ++kc) {
            f16x8 kf0 = *(const f16x8*)&Ks[kc * 2048 + (wc * 32 + ln) * 32 + quad * 8];
            f16x8 kf1 = *(const f16x8*)&Ks[kc * 2048 + (wc * 32 + 16 + ln) * 32 + quad * 8];
#pragma unroll
            for (int nt = 0; nt < 4; ++nt) {
                s[0][nt] = __builtin_amdgcn_mfma_f32_16x16x32_f16(kf0, qf[nt][kc], s[0][nt], 0, 0, 0);
                s[1][nt] = __builtin_amdgcn_mfma_f32_16x16x32_f16(kf1, qf[nt][kc], s[1][nt], 0, 0, 0);
            }
        }

        // exp (no max-sub), in-lane l partials, vectorized P write
#pragma unroll
        for (int mt = 0; mt < 2; ++mt) {
#pragma unroll
            for (int nt = 0; nt < 4; ++nt) {
                const float p0 = __expf(s[mt][nt][0]);
                const float p1 = __expf(s[mt][nt][1]);
                const float p2 = __expf(s[mt][nt][2]);
                const float p3 = __expf(s[mt][nt][3]);
                lp[nt] += (p0 + p1) + (p2 + p3);
                f16x4 pk;
                pk[0] = (f16)p0; pk[1] = (f16)p1; pk[2] = (f16)p2; pk[3] = (f16)p3;
                *(f16x4*)&Ps[wc * 4096 + (wq * 64 + nt * 16 + ln) * 32
                             + mt * 16 + quad * 4] = pk;
            }
        }
        __syncthreads();   // P visible to all waves

        // O += P V : wave quadrant [64 q][64 d], 32 MFMAs, 16 LDS reads
#pragma unroll
        for (int cc = 0; cc < 2; ++cc) {
            f16x8 pf[4];
#pragma unroll
            for (int mtq = 0; mtq < 4; ++mtq)
                pf[mtq] = *(const f16x8*)&Ps[cc * 4096 + (wq * 64 + mtq * 16 + ln) * 32 + quad * 8];
#pragma unroll
            for (int ntd = 0; ntd < 4; ++ntd) {
                f16x8 vf = *(const f16x8*)&Vs[cc * 4096 + (wc * 64 + ntd * 16 + ln) * 32 + quad * 8];
#pragma unroll
                for (int mtq = 0; mtq < 4; ++mtq)
                    o[mtq][ntd] = __builtin_amdgcn_mfma_f32_16x16x32_f16(
                        pf[mtq], vf, o[mtq][ntd], 0, 0, 0);
            }
        }
    }

    // finalize l: reduce over quads (c-spread), publish per (wc, q)
#pragma unroll
    for (int nt = 0; nt < 4; ++nt) {
        float v = lp[nt];
        v += __shfl_xor(v, 16, 64);
        v += __shfl_xor(v, 32, 64);
        lp[nt] = v;
    }
    if (quad == 0) {
#pragma unroll
        for (int nt = 0; nt < 4; ++nt)
            l_buf[wc * 128 + wq * 64 + nt * 16 + ln] = lp[nt];
    }
    __syncthreads();

    // epilogue: AO[b][s][h*DK + d] = o / l
    const int b = bh >> 4;
    const int h = bh & (NHEADS - 1);
#pragma unroll
    for (int mtq = 0; mtq < 4; ++mtq) {
#pragma unroll
        for (int reg = 0; reg < 4; ++reg) {
            const int ql = wq * 64 + mtq * 16 + quad * 4 + reg;
            const float inv = 1.0f / (l_buf[ql] + l_buf[128 + ql]);
            f16* dst = AO + ((size_t)b * S_LEN + q0 + ql) * DMODEL + h * DK + wc * 64;
#pragma unroll
            for (int ntd = 0; ntd < 4; ++ntd)
                dst[ntd * 16 + ln] = (f16)(o[mtq][ntd][reg] * inv);
        }
    }
}

// ---------------------------------------------------------------------------
extern "C" void kernel_launch(void* const* d_in, const int* in_sizes, int n_in,
                              void* d_out, int out_size, void* d_ws, size_t ws_size,
                              hipStream_t stream)
{
    (void)in_sizes; (void)n_in; (void)out_size; (void)ws_size;
    const float* query = (const float*)d_in[0];
    const float* key_  = (const float*)d_in[1];
    const float* value = (const float*)d_in[2];
    const float* w_q = (const float*)d_in[3];
    const float* b_q = (const float*)d_in[4];
    const float* w_k = (const float*)d_in[5];
    const float* b_k = (const float*)d_in[6];
    const float* w_v = (const float*)d_in[7];
    const float* b_v = (const float*)d_in[8];
    const float* w_o = (const float*)d_in[9];
    const float* b_o = (const float*)d_in[10];
    const float* s_alpha = (const float*)d_in[11];
    const float* s_beta  = (const float*)d_in[12];
    float* out = (float*)d_out;

    const size_t T = (size_t)MROWS * DMODEL;    // 8,388,608
    const size_t Wn = (size_t)DMODEL * DMODEL;  // 4,194,304
    f16* base = (f16*)d_ws;
    f16* c_q = base;              // reused as Kh AFTER Q-proj dispatch completes
    f16* c_k = base + T;          // reused as VT AFTER K-proj dispatch completes
    f16* c_v = base + 2 * T;      // reused as AOh AFTER V-proj dispatch completes
    f16* Qh  = base + 3 * T;
    f16* wq16 = base + 4 * T;
    f16* wk16 = wq16 + Wn;
    f16* wv16 = wk16 + Wn;
    f16* wo16 = wv16 + Wn;
    f16* Kh  = c_q;
    f16* VT  = c_k;
    f16* AOh = c_v;

    dim3 blk(256);

    cvt_all<<<dim3(40960), blk, 0, stream>>>(query, key_, value, w_q, w_k, w_v, w_o,
                                             c_q, c_k, c_v, wq16, wk16, wv16, wo16);

    // Three SEQUENTIAL projection dispatches: stream ordering legalizes the
    // buffer reuse (Kh=c_q written only after Q-proj finished reading c_q, etc).
    proj_gemm<<<dim3(512), blk, 0, stream>>>(c_q, wq16, b_q, Qh, 3, s_alpha, s_beta);
    proj_gemm<<<dim3(512), blk, 0, stream>>>(c_k, wk16, b_k, Kh, 1, nullptr, nullptr);
    proj_gemm<<<dim3(512), blk, 0, stream>>>(c_v, wv16, b_v, VT, 2, nullptr, nullptr);

    dim3 flash_grid(S_LEN / 128, 2 * NHEADS);     // (16, 32)
    flash_v4<<<flash_grid, blk, 0, stream>>>(Qh, Kh, VT, AOh);

    proj_gemm<<<dim3(512), blk, 0, stream>>>(AOh, wo16, b_o, out, 0, nullptr, nullptr);
}